// Round 4
// baseline (410.988 us; speedup 1.0000x reference)
//
#include <hip/hip_runtime.h>
#include <hip/hip_bf16.h>
#include <math.h>

#define S_LEN 2048
#define BATCH 2
#define EMB   1024
#define NH    16
#define DH    64
#define E3    3072
#define FF    4096
#define PP    64
// 0.125 * log2(e): folded into q-cols + peQ so attn can use exp2 directly.
#define QSCALE 0.18033688f
#define LOG2E  1.4426950408889634f

typedef __bf16 bf16x8 __attribute__((ext_vector_type(8)));
typedef float  floatx4 __attribute__((ext_vector_type(4)));

__device__ __forceinline__ void load_lds16(const void* g, void* l) {
  __builtin_amdgcn_global_load_lds(
      (const __attribute__((address_space(1))) void*)g,
      (__attribute__((address_space(3))) void*)l, 16, 0, 0);
}

// ---------------- fused fp32 -> bf16 convert, 5 segments ----------------
__global__ __launch_bounds__(256) void cvt5_kernel(
    const float* __restrict__ in0, __hip_bfloat16* __restrict__ o0,
    const float* __restrict__ in1, __hip_bfloat16* __restrict__ o1,
    const float* __restrict__ in2, __hip_bfloat16* __restrict__ o2,
    const float* __restrict__ in3, __hip_bfloat16* __restrict__ o3,
    const float* __restrict__ in4, __hip_bfloat16* __restrict__ o4)
{
  int bid = blockIdx.x;
  const float* in; __hip_bfloat16* out; int base;
  if      (bid < 2048) { in = in0; out = o0; base = bid; }
  else if (bid < 3584) { in = in1; out = o1; base = bid - 2048; }
  else if (bid < 4096) { in = in2; out = o2; base = bid - 3584; }
  else if (bid < 6144) { in = in3; out = o3; base = bid - 4096; }
  else                 { in = in4; out = o4; base = bid - 6144; }
  int i = (base * 256 + threadIdx.x) * 8;
  float4 a = *(const float4*)&in[i];
  float4 b = *(const float4*)&in[i + 4];
  __hip_bfloat16 t[8];
  t[0] = __float2bfloat16(a.x); t[1] = __float2bfloat16(a.y);
  t[2] = __float2bfloat16(a.z); t[3] = __float2bfloat16(a.w);
  t[4] = __float2bfloat16(b.x); t[5] = __float2bfloat16(b.y);
  t[6] = __float2bfloat16(b.z); t[7] = __float2bfloat16(b.w);
  *(float4*)&out[i] = *(float4*)t;
}

// ---------------- pos-embedding projection + L1 norm -> bf16 ----------------
// peT[b][s][q] = pe (unscaled, K'-side); peQ = pe * log2(e) (Q'-side).
__global__ __launch_bounds__(64) void pe_kernel(
    const float* __restrict__ pos_embed, const float* __restrict__ pos_w,
    const float* __restrict__ pos_b, __hip_bfloat16* __restrict__ peT,
    __hip_bfloat16* __restrict__ peQ)
{
  __shared__ float pw[PP * PP];
  int tid = threadIdx.x;
  for (int i = 0; i < PP; ++i) pw[i * PP + tid] = pos_w[i * PP + tid];
  __syncthreads();
  int s = blockIdx.x * 64 + tid;
  int b = blockIdx.y;
  float acc[PP];
#pragma unroll
  for (int q = 0; q < PP; ++q) acc[q] = pos_b[q];
  for (int p = 0; p < PP; ++p) {
    float x = pos_embed[(size_t)(b * PP + p) * S_LEN + s];
#pragma unroll
    for (int q = 0; q < PP; ++q) acc[q] += pw[q * PP + p] * x;
  }
  float l1 = 0.f;
#pragma unroll
  for (int q = 0; q < PP; ++q) l1 += fabsf(acc[q]);
  float inv = 1.f / fmaxf(l1, 1e-12f);
  __hip_bfloat16 tmp[PP], tmq[PP];
#pragma unroll
  for (int q = 0; q < PP; ++q) {
    float v = acc[q] * inv;
    tmp[q] = __float2bfloat16(v);
    tmq[q] = __float2bfloat16(v * LOG2E);
  }
  float4* dst = (float4*)&peT[((size_t)b * S_LEN + s) * PP];
  float4* dsq = (float4*)&peQ[((size_t)b * S_LEN + s) * PP];
#pragma unroll
  for (int i = 0; i < 8; ++i) { dst[i] = ((float4*)tmp)[i]; dsq[i] = ((float4*)tmq)[i]; }
}

// ---------------- bf16 MFMA GEMM (128-class tiles): C = A @ W^T + bias ------
// ldA/ldW = leading dims (may exceed K for split-K chunks). blockIdx.z selects
// a K-chunk: A += z*strideA, W += z*strideW (column offsets), Cf += z*strideC;
// bias applied only on chunk 0.
template <int WR, int WC>
__global__ __launch_bounds__(256) void gemm_bf16(
    const __hip_bfloat16* __restrict__ A, const __hip_bfloat16* __restrict__ W,
    const float* __restrict__ bias, float* __restrict__ Cf,
    __hip_bfloat16* __restrict__ Cb, int M, int N, int K, int relu, int qkscale,
    int ldA, int ldW, long strideA, long strideW, long strideC)
{
  constexpr int BM = 2 * WR * 16;
  constexpr int BN = 2 * WC * 16;
  __shared__ __bf16 As[BM * 64];
  __shared__ __bf16 Bs[BN * 64];
  A += (size_t)blockIdx.z * strideA;
  W += (size_t)blockIdx.z * strideW;
  int tid = threadIdx.x;
  int bm = blockIdx.y * BM;
  int bn = blockIdx.x * BN;
  int wave = tid >> 6, lane = tid & 63;
  int wm = (wave & 1) * (WR * 16), wn = (wave >> 1) * (WC * 16);
  int srow = tid >> 3, scb = tid & 7;
  int gcb = scb ^ (srow & 7);
  const __hip_bfloat16* Ap = A + (size_t)(bm + srow) * ldA + gcb * 8;
  const __hip_bfloat16* Wp = W + (size_t)(bn + srow) * ldW + gcb * 8;
  __bf16* AsBase = As + tid * 8;
  __bf16* BsBase = Bs + tid * 8;
  int r15 = lane & 15, quad = lane >> 4;

  floatx4 acc[WR * WC];
#pragma unroll
  for (int i = 0; i < WR * WC; ++i) acc[i] = (floatx4){0.f, 0.f, 0.f, 0.f};

  for (int k0 = 0; k0 < K; k0 += 64) {
    __syncthreads();
#pragma unroll
    for (int io = 0; io < BM / 32; ++io)
      load_lds16(Ap + (size_t)(32 * io) * ldA + k0, AsBase + io * 2048);
#pragma unroll
    for (int io = 0; io < BN / 32; ++io)
      load_lds16(Wp + (size_t)(32 * io) * ldW + k0, BsBase + io * 2048);
    __syncthreads();
#pragma unroll
    for (int kc = 0; kc < 2; ++kc) {
      bf16x8 af[WR], bfv[WC];
      int kb = kc * 4 + quad;
#pragma unroll
      for (int i = 0; i < WR; ++i) {
        int rowa = wm + i * 16 + r15;
        af[i] = *(const bf16x8*)&As[rowa * 64 + (kb ^ (rowa & 7)) * 8];
      }
#pragma unroll
      for (int j = 0; j < WC; ++j) {
        int rowb = wn + j * 16 + r15;
        bfv[j] = *(const bf16x8*)&Bs[rowb * 64 + (kb ^ (rowb & 7)) * 8];
      }
#pragma unroll
      for (int i = 0; i < WR; ++i)
#pragma unroll
        for (int j = 0; j < WC; ++j)
          acc[i * WC + j] = __builtin_amdgcn_mfma_f32_16x16x32_bf16(
              af[i], bfv[j], acc[i * WC + j], 0, 0, 0);
    }
  }
  int crow0 = bm + wm + quad * 4;
  int ccol0 = bn + wn + r15;
  float* CfB = Cf ? Cf + (long)blockIdx.z * strideC : nullptr;
  __hip_bfloat16* CbB = Cb;
#pragma unroll
  for (int j = 0; j < WC; ++j) {
    int col = ccol0 + j * 16;
    float bv = (bias && blockIdx.z == 0) ? bias[col] : 0.f;
    float scale = (qkscale && col < EMB) ? QSCALE : 1.f;
#pragma unroll
    for (int i = 0; i < WR; ++i) {
#pragma unroll
      for (int r = 0; r < 4; ++r) {
        int row = crow0 + i * 16 + r;
        float v = (acc[i * WC + j][r] + bv) * scale;
        if (relu) v = fmaxf(v, 0.f);
        if (CfB) CfB[(size_t)row * N + col] = v;
        if (CbB) CbB[(size_t)row * N + col] = __float2bfloat16(v);
      }
    }
  }
}

// ---------------- 256x256 8-phase bf16 GEMM (harness-verified) --------------
__global__ __launch_bounds__(512, 2) void gemm256_bf16(
    const __hip_bfloat16* __restrict__ A, const __hip_bfloat16* __restrict__ W,
    const float* __restrict__ bias, __hip_bfloat16* __restrict__ Cb,
    int M, int N, int K, int relu, int qkscale)
{
  __shared__ __bf16 As[2][16384];
  __shared__ __bf16 Bs[2][16384];
  const int tid = threadIdx.x;
  const int bm = blockIdx.y * 256;
  const int bn = blockIdx.x * 256;
  const int wave = tid >> 6, lane = tid & 63;
  const int wm = (wave >> 2) * 128, wn = (wave & 3) * 64;
  const int r15 = lane & 15, quad = lane >> 4;
  const int srow = tid >> 3, scb = tid & 7;
  const int NT = K >> 6;

  const __hip_bfloat16* Ap = A + (size_t)bm * K;
  const __hip_bfloat16* Wp = W + (size_t)bn * K;

  auto stageA = [&](int buf, int k0, int h) {
#pragma unroll
    for (int io = 0; io < 2; ++io) {
      int row = h * 128 + io * 64 + srow;
      int gcb = scb ^ (row & 7);
      load_lds16(Ap + (size_t)row * K + k0 + gcb * 8,
                 &As[buf][(h * 128 + io * 64) * 64] + tid * 8);
    }
  };
  auto stageB = [&](int buf, int k0, int h) {
#pragma unroll
    for (int io = 0; io < 2; ++io) {
      int row = h * 128 + io * 64 + srow;
      int gcb = scb ^ (row & 7);
      load_lds16(Wp + (size_t)row * K + k0 + gcb * 8,
                 &Bs[buf][(h * 128 + io * 64) * 64] + tid * 8);
    }
  };

  floatx4 acc[8][4];
#pragma unroll
  for (int i = 0; i < 8; ++i)
#pragma unroll
    for (int jn = 0; jn < 4; ++jn) acc[i][jn] = (floatx4){0.f, 0.f, 0.f, 0.f};

  stageA(0, 0, 0); stageA(0, 0, 1);
  stageB(0, 0, 0); stageB(0, 0, 1);
  stageA(1, 64, 0); stageA(1, 64, 1);
  asm volatile("s_waitcnt vmcnt(4)" ::: "memory");
  __builtin_amdgcn_s_barrier();
  __builtin_amdgcn_sched_barrier(0);

#define PHASE_BAR() do { __builtin_amdgcn_sched_barrier(0); \
                         __builtin_amdgcn_s_barrier();      \
                         __builtin_amdgcn_sched_barrier(0); } while (0)

  bf16x8 af[4][2], bfr[4][2];
  for (int j = 0; j < NT; ++j) {
    const int cur = j & 1, nxt = cur ^ 1;
    const int k1 = (j + 1) << 6, k2 = (j + 2) << 6;

#pragma unroll
    for (int i = 0; i < 4; ++i) {
      int row = wm + i * 16 + r15;
#pragma unroll
      for (int kc = 0; kc < 2; ++kc)
        af[i][kc] = *(const bf16x8*)&As[cur][row * 64 + (((kc * 4 + quad) ^ (row & 7)) * 8)];
    }
#pragma unroll
    for (int jn = 0; jn < 2; ++jn) {
      int row = wn + jn * 16 + r15;
#pragma unroll
      for (int kc = 0; kc < 2; ++kc)
        bfr[jn][kc] = *(const bf16x8*)&Bs[cur][row * 64 + (((kc * 4 + quad) ^ (row & 7)) * 8)];
    }
    if (j + 1 < NT) stageB(nxt, k1, 0);
    PHASE_BAR();
    __builtin_amdgcn_s_setprio(1);
#pragma unroll
    for (int i = 0; i < 4; ++i)
#pragma unroll
      for (int jn = 0; jn < 2; ++jn)
#pragma unroll
        for (int kc = 0; kc < 2; ++kc)
          acc[i][jn] = __builtin_amdgcn_mfma_f32_16x16x32_bf16(
              af[i][kc], bfr[jn][kc], acc[i][jn], 0, 0, 0);
    __builtin_amdgcn_s_setprio(0);
    PHASE_BAR();

#pragma unroll
    for (int jn = 2; jn < 4; ++jn) {
      int row = wn + jn * 16 + r15;
#pragma unroll
      for (int kc = 0; kc < 2; ++kc)
        bfr[jn][kc] = *(const bf16x8*)&Bs[cur][row * 64 + (((kc * 4 + quad) ^ (row & 7)) * 8)];
    }
    if (j + 1 < NT) stageB(nxt, k1, 1);
    PHASE_BAR();
    __builtin_amdgcn_s_setprio(1);
#pragma unroll
    for (int i = 0; i < 4; ++i)
#pragma unroll
      for (int jn = 2; jn < 4; ++jn)
#pragma unroll
        for (int kc = 0; kc < 2; ++kc)
          acc[i][jn] = __builtin_amdgcn_mfma_f32_16x16x32_bf16(
              af[i][kc], bfr[jn][kc], acc[i][jn], 0, 0, 0);
    __builtin_amdgcn_s_setprio(0);
    PHASE_BAR();

#pragma unroll
    for (int i = 0; i < 4; ++i) {
      int row = wm + (i + 4) * 16 + r15;
#pragma unroll
      for (int kc = 0; kc < 2; ++kc)
        af[i][kc] = *(const bf16x8*)&As[cur][row * 64 + (((kc * 4 + quad) ^ (row & 7)) * 8)];
    }
    PHASE_BAR();
    __builtin_amdgcn_s_setprio(1);
#pragma unroll
    for (int i = 0; i < 4; ++i)
#pragma unroll
      for (int jn = 2; jn < 4; ++jn)
#pragma unroll
        for (int kc = 0; kc < 2; ++kc)
          acc[i + 4][jn] = __builtin_amdgcn_mfma_f32_16x16x32_bf16(
              af[i][kc], bfr[jn][kc], acc[i + 4][jn], 0, 0, 0);
    __builtin_amdgcn_s_setprio(0);
    PHASE_BAR();

    if (j + 2 < NT) { stageA(cur, k2, 0); stageA(cur, k2, 1); }
    if (j < NT - 2) asm volatile("s_waitcnt vmcnt(4)" ::: "memory");
    else            asm volatile("s_waitcnt vmcnt(0)" ::: "memory");
    PHASE_BAR();
    __builtin_amdgcn_s_setprio(1);
#pragma unroll
    for (int i = 0; i < 4; ++i)
#pragma unroll
      for (int jn = 0; jn < 2; ++jn)
#pragma unroll
        for (int kc = 0; kc < 2; ++kc)
          acc[i + 4][jn] = __builtin_amdgcn_mfma_f32_16x16x32_bf16(
              af[i][kc], bfr[jn][kc], acc[i + 4][jn], 0, 0, 0);
    __builtin_amdgcn_s_setprio(0);
    PHASE_BAR();
  }
#undef PHASE_BAR

  const int crow0 = bm + wm + quad * 4;
  const int ccol0 = bn + wn + r15;
#pragma unroll
  for (int jn = 0; jn < 4; ++jn) {
    int col = ccol0 + jn * 16;
    float bv = bias ? bias[col] : 0.f;
    float scale = (qkscale && col < EMB) ? QSCALE : 1.f;
#pragma unroll
    for (int i = 0; i < 8; ++i) {
#pragma unroll
      for (int r = 0; r < 4; ++r) {
        int row = crow0 + i * 16 + r;
        float v = (acc[i][jn][r] + bv) * scale;
        if (relu) v = fmaxf(v, 0.f);
        Cb[(size_t)row * N + col] = __float2bfloat16(v);
      }
    }
  }
}

// ---------------- transpose V: vT[b, c, t] = qkv_bf[t*B+b, 2E + c] ----------
__global__ __launch_bounds__(256) void transpose_v(
    const __hip_bfloat16* __restrict__ qkv, __hip_bfloat16* __restrict__ vT)
{
  __shared__ __hip_bfloat16 tile[64][72];
  int c0 = blockIdx.x * 64, t0 = blockIdx.y * 64, b = blockIdx.z;
  int tid = threadIdx.x;
#pragma unroll
  for (int i = 0; i < 2; ++i) {
    int k = tid * 2 + i;
    int row = k >> 3, col = (k & 7) * 8;
    float4 v = *(const float4*)&qkv[((size_t)(t0 + row) * BATCH + b) * E3 + 2 * EMB + c0 + col];
    __hip_bfloat16 tmp[8];
    *(float4*)tmp = v;
#pragma unroll
    for (int j = 0; j < 8; ++j) tile[row][col + j] = tmp[j];
  }
  __syncthreads();
#pragma unroll
  for (int i = 0; i < 2; ++i) {
    int k = tid * 2 + i;
    int crow = k >> 3, tcol = (k & 7) * 8;
    __hip_bfloat16 tmp[8];
#pragma unroll
    for (int j = 0; j < 8; ++j) tmp[j] = tile[tcol + j][crow];
    *(float4*)&vT[((size_t)(b * EMB + c0 + crow)) * S_LEN + t0 + tcol] = *(float4*)tmp;
  }
}

// ---------------- MFMA flash attention, S^T form, no-max softmax -------------
// 8 waves x 16 q-rows. Q-side operands pre-scaled by log2(e) (q cols at the
// qkv GEMM epilogue, pe via the peQ buffer) so P = exp2(S') with one hw
// v_exp and no clamp/mul. K-side (staged) uses unscaled k / peT.
__global__ __launch_bounds__(512, 4) void attn_mfma(
    const __hip_bfloat16* __restrict__ qkv,   // [S*B][E3] bf16 (q pre-scaled)
    const __hip_bfloat16* __restrict__ vT,    // [B][EMB][S] bf16
    const __hip_bfloat16* __restrict__ peT,   // [B][S][PP] bf16 (K'-side)
    const __hip_bfloat16* __restrict__ peQ,   // [B][S][PP] bf16 (Q'-side, xlog2e)
    __hip_bfloat16* __restrict__ ctx)         // [S*B][EMB] bf16
{
  __shared__ __bf16 Ks[2][4096];   // 16 KB  [key][d]  swizzled (k part)
  __shared__ __bf16 Kp[2][4096];   // 16 KB  [key][p]  swizzled (pe part)
  __shared__ __bf16 Vs[2][4096];   // 16 KB  [d][t]    swizzled
  __shared__ __bf16 Ps[8192];      // 16 KB  per wave: [query][key] swizzled
  int tid = threadIdx.x;
  int q0 = blockIdx.x * 128, h = blockIdx.y, b = blockIdx.z;
  int w = tid >> 6, lane = tid & 63, quad = lane >> 4, r15 = lane & 15;
  int srow = tid >> 3, scb = tid & 7;
  int x7 = r15 & 7;

  const __hip_bfloat16* kbase = qkv + EMB + (size_t)h * DH;
  const __hip_bfloat16* vbase = vT + ((size_t)b * EMB + h * DH) * S_LEN;
  const __hip_bfloat16* pkbase = peT + (size_t)b * S_LEN * PP;
  const __hip_bfloat16* pqbase = peQ + (size_t)b * S_LEN * PP;

  // ---- Q' fragments straight to registers (B-operand layout) ----
  bf16x8 qa[4];
  {
    int qrow = q0 + w * 16 + r15;
#pragma unroll
    for (int kc = 0; kc < 2; ++kc)
      qa[kc] = *(const bf16x8*)&qkv[
          ((size_t)qrow * BATCH + b) * E3 + h * DH + kc * 32 + quad * 8];
#pragma unroll
    for (int kc = 0; kc < 2; ++kc)
      qa[2 + kc] = *(const bf16x8*)&pqbase[
          (size_t)qrow * PP + kc * 32 + quad * 8];
  }

  // ---- stage first K'/V tile ----
  {
    int row = srow;
    int gcb = scb ^ (row & 7);
    load_lds16(kbase + ((size_t)row * BATCH + b) * E3 + gcb * 8, Ks[0] + tid * 8);
    load_lds16(pkbase + (size_t)row * PP + gcb * 8, Kp[0] + tid * 8);
    load_lds16(vbase + (size_t)row * S_LEN + gcb * 8, Vs[0] + tid * 8);
  }
  __syncthreads();

  floatx4 of[4];
#pragma unroll
  for (int j = 0; j < 4; ++j) of[j] = (floatx4){0.f, 0.f, 0.f, 0.f};
  float lp = 0.f;

  __bf16* pw = Ps + w * 1024;

  for (int kt = 0; kt < 32; ++kt) {
    int cur = kt & 1;
    int t0 = kt * 64;
    // ---- stage next K'/V tile into the other buffer ----
    if (kt < 31) {
      int tn = t0 + 64;
      int nb = cur ^ 1;
      int row = srow;
      int gcb = scb ^ (row & 7);
      load_lds16(kbase + ((size_t)(tn + row) * BATCH + b) * E3 + gcb * 8,
                 Ks[nb] + tid * 8);
      load_lds16(pkbase + (size_t)(tn + row) * PP + gcb * 8,
                 Kp[nb] + tid * 8);
      load_lds16(vbase + (size_t)row * S_LEN + tn + gcb * 8,
                 Vs[nb] + tid * 8);
    }

    // ---- S^T = K' Q'^T (A = K' rows=keys, B = Q'^T cols=queries) ----
    floatx4 sf[4];
#pragma unroll
    for (int j = 0; j < 4; ++j) sf[j] = (floatx4){0.f, 0.f, 0.f, 0.f};
    __builtin_amdgcn_s_setprio(1);
#pragma unroll
    for (int j = 0; j < 4; ++j) {
      int rowk = j * 16 + r15;
      int rx = rowk & 7;
      bf16x8 kf0 = *(const bf16x8*)&Ks[cur][rowk * 64 + ((quad ^ rx)) * 8];
      bf16x8 kf1 = *(const bf16x8*)&Ks[cur][rowk * 64 + (((4 + quad) ^ rx)) * 8];
      bf16x8 kp0 = *(const bf16x8*)&Kp[cur][rowk * 64 + ((quad ^ rx)) * 8];
      bf16x8 kp1 = *(const bf16x8*)&Kp[cur][rowk * 64 + (((4 + quad) ^ rx)) * 8];
      sf[j] = __builtin_amdgcn_mfma_f32_16x16x32_bf16(kf0, qa[0], sf[j], 0, 0, 0);
      sf[j] = __builtin_amdgcn_mfma_f32_16x16x32_bf16(kf1, qa[1], sf[j], 0, 0, 0);
      sf[j] = __builtin_amdgcn_mfma_f32_16x16x32_bf16(kp0, qa[2], sf[j], 0, 0, 0);
      sf[j] = __builtin_amdgcn_mfma_f32_16x16x32_bf16(kp1, qa[3], sf[j], 0, 0, 0);
    }
    __builtin_amdgcn_s_setprio(0);

    // ---- exp2 (args pre-scaled by log2e; bounded, no clamp), pack P^T ----
#pragma unroll
    for (int j = 0; j < 4; ++j) {
      float e0 = exp2f(sf[j][0]);
      float e1 = exp2f(sf[j][1]);
      float e2 = exp2f(sf[j][2]);
      float e3 = exp2f(sf[j][3]);
      lp += (e0 + e1) + (e2 + e3);
      __hip_bfloat16 t4[4];
      t4[0] = __float2bfloat16(e0); t4[1] = __float2bfloat16(e1);
      t4[2] = __float2bfloat16(e2); t4[3] = __float2bfloat16(e3);
      int addr = r15 * 64 + (((j * 2 + (quad >> 1)) ^ x7) * 8) + (quad & 1) * 4;
      *(float2*)&pw[addr] = *(float2*)t4;
    }
    __asm__ volatile("s_waitcnt lgkmcnt(0)" ::: "memory");

    // ---- O^T += V^T P^T  (A = V^T rows=d, B = P^T cols=queries) ----
    bf16x8 pb0 = *(const bf16x8*)&pw[r15 * 64 + ((quad ^ x7) * 8)];
    bf16x8 pb1 = *(const bf16x8*)&pw[r15 * 64 + (((4 + quad) ^ x7) * 8)];
    __builtin_amdgcn_s_setprio(1);
#pragma unroll
    for (int jd = 0; jd < 4; ++jd) {
      int rowd = jd * 16 + r15;
      bf16x8 vb0 = *(const bf16x8*)&Vs[cur][rowd * 64 + (quad ^ (rowd & 7)) * 8];
      bf16x8 vb1 = *(const bf16x8*)&Vs[cur][rowd * 64 + ((4 + quad) ^ (rowd & 7)) * 8];
      of[jd] = __builtin_amdgcn_mfma_f32_16x16x32_bf16(vb0, pb0, of[jd], 0, 0, 0);
      of[jd] = __builtin_amdgcn_mfma_f32_16x16x32_bf16(vb1, pb1, of[jd], 0, 0, 0);
    }
    __builtin_amdgcn_s_setprio(0);
    __syncthreads();   // waves done with bufs[cur]; next-tile staging drained
  }

  // ---- epilogue: reduce l over quads, O^T / l, packed 8B stores ----
  {
    float l = lp;
    l += __shfl_xor(l, 16, 64);
    l += __shfl_xor(l, 32, 64);
    float inv = 1.f / l;
    size_t rbase = ((size_t)(q0 + w * 16 + r15) * BATCH + b) * EMB + h * DH;
#pragma unroll
    for (int jd = 0; jd < 4; ++jd) {
      __hip_bfloat16 o4[4];
      o4[0] = __float2bfloat16(of[jd][0] * inv);
      o4[1] = __float2bfloat16(of[jd][1] * inv);
      o4[2] = __float2bfloat16(of[jd][2] * inv);
      o4[3] = __float2bfloat16(of[jd][3] * inv);
      *(float2*)&ctx[rbase + jd * 16 + quad * 4] = *(float2*)o4;
    }
  }
}

// ---------------- layernorm(x1+x2)*g + b, fp32 out + optional bf16 out -------
__global__ __launch_bounds__(256) void ln_kernel(
    const float* __restrict__ x1, const float* __restrict__ x2,
    const float* __restrict__ g, const float* __restrict__ bb,
    float* __restrict__ out, __hip_bfloat16* __restrict__ out_bf)
{
  int row = blockIdx.x;
  int tid = threadIdx.x;
  const float* p1 = x1 + (size_t)row * EMB;
  const float* p2 = x2 + (size_t)row * EMB;
  float4 v1 = *(const float4*)&p1[tid * 4];
  float4 v2 = *(const float4*)&p2[tid * 4];
  float x[4] = {v1.x + v2.x, v1.y + v2.y, v1.z + v2.z, v1.w + v2.w};
  float s = x[0] + x[1] + x[2] + x[3];
  float s2 = x[0] * x[0] + x[1] * x[1] + x[2] * x[2] + x[3] * x[3];
#pragma unroll
  for (int off = 32; off >= 1; off >>= 1) {
    s  += __shfl_xor(s, off, 64);
    s2 += __shfl_xor(s2, off, 64);
  }
  __shared__ float ws1[4], ws2[4];
  int wid = tid >> 6, lane = tid & 63;
  if (lane == 0) { ws1[wid] = s; ws2[wid] = s2; }
  __syncthreads();
  s  = ws1[0] + ws1[1] + ws1[2] + ws1[3];
  s2 = ws2[0] + ws2[1] + ws2[2] + ws2[3];
  float mean = s * (1.f / EMB);
  float var  = s2 * (1.f / EMB) - mean * mean;
  float inv  = rsqrtf(var + 1e-5f);
  float4 gv = *(const float4*)&g[tid * 4];
  float4 bv = *(const float4*)&bb[tid * 4];
  float4 o;
  o.x = (x[0] - mean) * inv * gv.x + bv.x;
  o.y = (x[1] - mean) * inv * gv.y + bv.y;
  o.z = (x[2] - mean) * inv * gv.z + bv.z;
  o.w = (x[3] - mean) * inv * gv.w + bv.w;
  *(float4*)&out[(size_t)row * EMB + tid * 4] = o;
  if (out_bf) {
    __hip_bfloat16 t[4];
    t[0] = __float2bfloat16(o.x); t[1] = __float2bfloat16(o.y);
    t[2] = __float2bfloat16(o.z); t[3] = __float2bfloat16(o.w);
    *(float2*)&out_bf[(size_t)row * EMB + tid * 4] = *(float2*)t;
  }
}

// ---------------- layernorm(x1+x2+x3)*g + b, fp32 out (split-K ff2 sum) -----
__global__ __launch_bounds__(256) void ln3_kernel(
    const float* __restrict__ x1, const float* __restrict__ x2,
    const float* __restrict__ x3,
    const float* __restrict__ g, const float* __restrict__ bb,
    float* __restrict__ out)
{
  int row = blockIdx.x;
  int tid = threadIdx.x;
  const float* p1 = x1 + (size_t)row * EMB;
  const float* p2 = x2 + (size_t)row * EMB;
  const float* p3 = x3 + (size_t)row * EMB;
  float4 v1 = *(const float4*)&p1[tid * 4];
  float4 v2 = *(const float4*)&p2[tid * 4];
  float4 v3 = *(const float4*)&p3[tid * 4];
  float x[4] = {v1.x + v2.x + v3.x, v1.y + v2.y + v3.y,
                v1.z + v2.z + v3.z, v1.w + v2.w + v3.w};
  float s = x[0] + x[1] + x[2] + x[3];
  float s2 = x[0] * x[0] + x[1] * x[1] + x[2] * x[2] + x[3] * x[3];
#pragma unroll
  for (int off = 32; off >= 1; off >>= 1) {
    s  += __shfl_xor(s, off, 64);
    s2 += __shfl_xor(s2, off, 64);
  }
  __shared__ float ws1[4], ws2[4];
  int wid = tid >> 6, lane = tid & 63;
  if (lane == 0) { ws1[wid] = s; ws2[wid] = s2; }
  __syncthreads();
  s  = ws1[0] + ws1[1] + ws1[2] + ws1[3];
  s2 = ws2[0] + ws2[1] + ws2[2] + ws2[3];
  float mean = s * (1.f / EMB);
  float var  = s2 * (1.f / EMB) - mean * mean;
  float inv  = rsqrtf(var + 1e-5f);
  float4 gv = *(const float4*)&g[tid * 4];
  float4 bv = *(const float4*)&bb[tid * 4];
  float4 o;
  o.x = (x[0] - mean) * inv * gv.x + bv.x;
  o.y = (x[1] - mean) * inv * gv.y + bv.y;
  o.z = (x[2] - mean) * inv * gv.z + bv.z;
  o.w = (x[3] - mean) * inv * gv.w + bv.w;
  *(float4*)&out[(size_t)row * EMB + tid * 4] = o;
}

extern "C" void kernel_launch(void* const* d_in, const int* in_sizes, int n_in,
                              void* d_out, int out_size, void* d_ws, size_t ws_size,
                              hipStream_t stream)
{
  const float* src       = (const float*)d_in[0];
  const float* pos_embed = (const float*)d_in[1];
  const float* in_proj_w = (const float*)d_in[2];
  const float* in_proj_b = (const float*)d_in[3];
  const float* out_w     = (const float*)d_in[4];
  const float* out_b     = (const float*)d_in[5];
  const float* lin1_w    = (const float*)d_in[6];
  const float* lin1_b    = (const float*)d_in[7];
  const float* lin2_w    = (const float*)d_in[8];
  const float* lin2_b    = (const float*)d_in[9];
  const float* ln1_g     = (const float*)d_in[10];
  const float* ln1_b     = (const float*)d_in[11];
  const float* ln2_g     = (const float*)d_in[12];
  const float* ln2_b     = (const float*)d_in[13];
  const float* pos_w     = (const float*)d_in[14];
  const float* pos_b     = (const float*)d_in[15];
  float* out = (float*)d_out;
  float* ws  = (float*)d_ws;

  // ---- workspace layout (float units) ----
  __hip_bfloat16* peT    = (__hip_bfloat16*)ws;                // 262,144 el -> 131,072 fl
  __hip_bfloat16* peQ    = (__hip_bfloat16*)(ws + 131072);     // 262,144 el -> 262,144 fl
  __hip_bfloat16* qkv_bf = (__hip_bfloat16*)(ws + 8519680);    // 12,582,912 el -> 14,811,136
  __hip_bfloat16* vT_bf  = (__hip_bfloat16*)(ws + 14811136);   // 4,194,304 el -> 16,908,288
  __hip_bfloat16* src_bf = (__hip_bfloat16*)(ws + 16908288);   // 4,194,304 el -> 19,005,440
  __hip_bfloat16* inw_bf  = (__hip_bfloat16*)(ws + 19005440);  // 3,145,728 el -> 20,578,304
  __hip_bfloat16* outw_bf = (__hip_bfloat16*)(ws + 20578304);  // 1,048,576 el -> 21,102,592
  __hip_bfloat16* ctx_bf = (__hip_bfloat16*)(ws + 21102592);   // 4,194,304 el -> 23,199,744
  __hip_bfloat16* l1w_bf = (__hip_bfloat16*)(ws + 23199744);   // 4,194,304 el -> 25,296,896
  __hip_bfloat16* l2w_bf = (__hip_bfloat16*)(ws + 25296896);   // 4,194,304 el -> 27,394,048
  float* proj            = ws + 27394048;                      // 4,194,304 -> 31,588,352
  // phase-2 reuse (peT/peQ/qkv/vT/src_bf dead after their consumers):
  __hip_bfloat16* x_bf   = (__hip_bfloat16*)ws;                // 4,194,304 el -> 2,097,152 fl
  float* xbuf            = ws + 2097152;                       // 4,194,304 -> 6,291,456
  __hip_bfloat16* h1_bf  = (__hip_bfloat16*)(ws + 6291456);    // 16,777,216 el -> 14,680,064 fl
  float* proj2           = ws + 14811136;                      // 4,194,304 -> 19,005,440 (old vT+src_bf region)

  const int M = S_LEN * BATCH;  // 4096 rows, row = s*B + b

  cvt5_kernel<<<8192, 256, 0, stream>>>(
      src, src_bf, in_proj_w, inw_bf, out_w, outw_bf,
      lin1_w, l1w_bf, lin2_w, l2w_bf);
  pe_kernel<<<dim3(S_LEN / 64, BATCH), 64, 0, stream>>>(pos_embed, pos_w, pos_b, peT, peQ);
  // qkv = src @ in_proj_w^T + b, q-cols pre-scaled by 0.125*log2e
  gemm256_bf16<<<dim3(E3 / 256, M / 256), 512, 0, stream>>>(
      src_bf, inw_bf, in_proj_b, qkv_bf, M, E3, EMB, 0, 1);
  transpose_v<<<dim3(EMB / 64, S_LEN / 64, BATCH), 256, 0, stream>>>(qkv_bf, vT_bf);
  attn_mfma<<<dim3(S_LEN / 128, NH, BATCH), 512, 0, stream>>>(
      qkv_bf, vT_bf, peT, peQ, ctx_bf);
  // attn_out = ctx @ out_w^T + b
  gemm_bf16<2, 4><<<dim3(EMB / 128, M / 64, 1), 256, 0, stream>>>(
      ctx_bf, outw_bf, out_b, proj, nullptr, M, EMB, EMB, 0, 0, EMB, EMB, 0, 0, 0);
  ln_kernel<<<dim3(M), 256, 0, stream>>>(src, proj, ln1_g, ln1_b, xbuf, x_bf);
  // ff1 = relu(x @ lin1_w^T + b)  (8-phase 256^2)
  gemm256_bf16<<<dim3(FF / 256, M / 256), 512, 0, stream>>>(
      x_bf, l1w_bf, lin1_b, h1_bf, M, FF, EMB, 1, 0);
  // ff2 split-K x2: chunk z covers K-cols [z*2048, z*2048+2048); partials to
  // proj (z=0, +bias) and proj2 (z=1; strideC = proj2 - proj, negative ok).
  gemm_bf16<4, 4><<<dim3(EMB / 128, M / 128, 2), 256, 0, stream>>>(
      h1_bf, l2w_bf, lin2_b, proj, nullptr, M, EMB, FF / 2, 0, 0,
      FF, FF, FF / 2, FF / 2, (long)(proj2 - proj));
  ln3_kernel<<<dim3(M), 256, 0, stream>>>(xbuf, proj, proj2, ln2_g, ln2_b, out);
}

// Round 5
// 395.463 us; speedup vs baseline: 1.0393x; 1.0393x over previous
//
#include <hip/hip_runtime.h>
#include <hip/hip_bf16.h>
#include <math.h>

#define S_LEN 2048
#define BATCH 2
#define EMB   1024
#define NH    16
#define DH    64
#define E3    3072
#define FF    4096
#define PP    64
// 0.125 * log2(e): folded into q-cols + peQ so attn can use raw v_exp_f32
// (hardware exp2) with no clamp/multiply in the inner loop.
#define QSCALE 0.18033688f
#define LOG2E  1.4426950408889634f

typedef __bf16 bf16x8 __attribute__((ext_vector_type(8)));
typedef float  floatx4 __attribute__((ext_vector_type(4)));

__device__ __forceinline__ void load_lds16(const void* g, void* l) {
  __builtin_amdgcn_global_load_lds(
      (const __attribute__((address_space(1))) void*)g,
      (__attribute__((address_space(3))) void*)l, 16, 0, 0);
}

// raw hardware exp2: one v_exp_f32, no libm edge-case handling.
__device__ __forceinline__ float hw_exp2(float x) {
  float r;
  asm("v_exp_f32 %0, %1" : "=v"(r) : "v"(x));
  return r;
}

// ---------------- fused fp32 -> bf16 convert, 5 segments ----------------
__global__ __launch_bounds__(256) void cvt5_kernel(
    const float* __restrict__ in0, __hip_bfloat16* __restrict__ o0,
    const float* __restrict__ in1, __hip_bfloat16* __restrict__ o1,
    const float* __restrict__ in2, __hip_bfloat16* __restrict__ o2,
    const float* __restrict__ in3, __hip_bfloat16* __restrict__ o3,
    const float* __restrict__ in4, __hip_bfloat16* __restrict__ o4)
{
  int bid = blockIdx.x;
  const float* in; __hip_bfloat16* out; int base;
  if      (bid < 2048) { in = in0; out = o0; base = bid; }
  else if (bid < 3584) { in = in1; out = o1; base = bid - 2048; }
  else if (bid < 4096) { in = in2; out = o2; base = bid - 3584; }
  else if (bid < 6144) { in = in3; out = o3; base = bid - 4096; }
  else                 { in = in4; out = o4; base = bid - 6144; }
  int i = (base * 256 + threadIdx.x) * 8;
  float4 a = *(const float4*)&in[i];
  float4 b = *(const float4*)&in[i + 4];
  __hip_bfloat16 t[8];
  t[0] = __float2bfloat16(a.x); t[1] = __float2bfloat16(a.y);
  t[2] = __float2bfloat16(a.z); t[3] = __float2bfloat16(a.w);
  t[4] = __float2bfloat16(b.x); t[5] = __float2bfloat16(b.y);
  t[6] = __float2bfloat16(b.z); t[7] = __float2bfloat16(b.w);
  *(float4*)&out[i] = *(float4*)t;
}

// ---------------- pos-embedding projection + L1 norm -> bf16 ----------------
// peT[b][s][q] = pe (unscaled, K'-side); peQ = pe * log2(e) (Q'-side).
__global__ __launch_bounds__(64) void pe_kernel(
    const float* __restrict__ pos_embed, const float* __restrict__ pos_w,
    const float* __restrict__ pos_b, __hip_bfloat16* __restrict__ peT,
    __hip_bfloat16* __restrict__ peQ)
{
  __shared__ float pw[PP * PP];
  int tid = threadIdx.x;
  for (int i = 0; i < PP; ++i) pw[i * PP + tid] = pos_w[i * PP + tid];
  __syncthreads();
  int s = blockIdx.x * 64 + tid;
  int b = blockIdx.y;
  float acc[PP];
#pragma unroll
  for (int q = 0; q < PP; ++q) acc[q] = pos_b[q];
  for (int p = 0; p < PP; ++p) {
    float x = pos_embed[(size_t)(b * PP + p) * S_LEN + s];
#pragma unroll
    for (int q = 0; q < PP; ++q) acc[q] += pw[q * PP + p] * x;
  }
  float l1 = 0.f;
#pragma unroll
  for (int q = 0; q < PP; ++q) l1 += fabsf(acc[q]);
  float inv = 1.f / fmaxf(l1, 1e-12f);
  __hip_bfloat16 tmp[PP], tmq[PP];
#pragma unroll
  for (int q = 0; q < PP; ++q) {
    float v = acc[q] * inv;
    tmp[q] = __float2bfloat16(v);
    tmq[q] = __float2bfloat16(v * LOG2E);
  }
  float4* dst = (float4*)&peT[((size_t)b * S_LEN + s) * PP];
  float4* dsq = (float4*)&peQ[((size_t)b * S_LEN + s) * PP];
#pragma unroll
  for (int i = 0; i < 8; ++i) { dst[i] = ((float4*)tmp)[i]; dsq[i] = ((float4*)tmq)[i]; }
}

// ---------------- bf16 MFMA GEMM (128-class tiles): C = A @ W^T + bias ------
template <int WR, int WC>
__global__ __launch_bounds__(256) void gemm_bf16(
    const __hip_bfloat16* __restrict__ A, const __hip_bfloat16* __restrict__ W,
    const float* __restrict__ bias, float* __restrict__ Cf,
    __hip_bfloat16* __restrict__ Cb, int M, int N, int K, int relu, int qkscale,
    int ldA, int ldW, long strideA, long strideW, long strideC)
{
  constexpr int BM = 2 * WR * 16;
  constexpr int BN = 2 * WC * 16;
  __shared__ __bf16 As[BM * 64];
  __shared__ __bf16 Bs[BN * 64];
  A += (size_t)blockIdx.z * strideA;
  W += (size_t)blockIdx.z * strideW;
  int tid = threadIdx.x;
  int bm = blockIdx.y * BM;
  int bn = blockIdx.x * BN;
  int wave = tid >> 6, lane = tid & 63;
  int wm = (wave & 1) * (WR * 16), wn = (wave >> 1) * (WC * 16);
  int srow = tid >> 3, scb = tid & 7;
  int gcb = scb ^ (srow & 7);
  const __hip_bfloat16* Ap = A + (size_t)(bm + srow) * ldA + gcb * 8;
  const __hip_bfloat16* Wp = W + (size_t)(bn + srow) * ldW + gcb * 8;
  __bf16* AsBase = As + tid * 8;
  __bf16* BsBase = Bs + tid * 8;
  int r15 = lane & 15, quad = lane >> 4;

  floatx4 acc[WR * WC];
#pragma unroll
  for (int i = 0; i < WR * WC; ++i) acc[i] = (floatx4){0.f, 0.f, 0.f, 0.f};

  for (int k0 = 0; k0 < K; k0 += 64) {
    __syncthreads();
#pragma unroll
    for (int io = 0; io < BM / 32; ++io)
      load_lds16(Ap + (size_t)(32 * io) * ldA + k0, AsBase + io * 2048);
#pragma unroll
    for (int io = 0; io < BN / 32; ++io)
      load_lds16(Wp + (size_t)(32 * io) * ldW + k0, BsBase + io * 2048);
    __syncthreads();
#pragma unroll
    for (int kc = 0; kc < 2; ++kc) {
      bf16x8 af[WR], bfv[WC];
      int kb = kc * 4 + quad;
#pragma unroll
      for (int i = 0; i < WR; ++i) {
        int rowa = wm + i * 16 + r15;
        af[i] = *(const bf16x8*)&As[rowa * 64 + (kb ^ (rowa & 7)) * 8];
      }
#pragma unroll
      for (int j = 0; j < WC; ++j) {
        int rowb = wn + j * 16 + r15;
        bfv[j] = *(const bf16x8*)&Bs[rowb * 64 + (kb ^ (rowb & 7)) * 8];
      }
#pragma unroll
      for (int i = 0; i < WR; ++i)
#pragma unroll
        for (int j = 0; j < WC; ++j)
          acc[i * WC + j] = __builtin_amdgcn_mfma_f32_16x16x32_bf16(
              af[i], bfv[j], acc[i * WC + j], 0, 0, 0);
    }
  }
  int crow0 = bm + wm + quad * 4;
  int ccol0 = bn + wn + r15;
  float* CfB = Cf ? Cf + (long)blockIdx.z * strideC : nullptr;
  __hip_bfloat16* CbB = Cb;
#pragma unroll
  for (int j = 0; j < WC; ++j) {
    int col = ccol0 + j * 16;
    float bv = (bias && blockIdx.z == 0) ? bias[col] : 0.f;
    float scale = (qkscale && col < EMB) ? QSCALE : 1.f;
#pragma unroll
    for (int i = 0; i < WR; ++i) {
#pragma unroll
      for (int r = 0; r < 4; ++r) {
        int row = crow0 + i * 16 + r;
        float v = (acc[i * WC + j][r] + bv) * scale;
        if (relu) v = fmaxf(v, 0.f);
        if (CfB) CfB[(size_t)row * N + col] = v;
        if (CbB) CbB[(size_t)row * N + col] = __float2bfloat16(v);
      }
    }
  }
}

// ---------------- 256x256 8-phase bf16 GEMM (harness-verified) --------------
__global__ __launch_bounds__(512, 2) void gemm256_bf16(
    const __hip_bfloat16* __restrict__ A, const __hip_bfloat16* __restrict__ W,
    const float* __restrict__ bias, __hip_bfloat16* __restrict__ Cb,
    int M, int N, int K, int relu, int qkscale)
{
  __shared__ __bf16 As[2][16384];
  __shared__ __bf16 Bs[2][16384];
  const int tid = threadIdx.x;
  const int bm = blockIdx.y * 256;
  const int bn = blockIdx.x * 256;
  const int wave = tid >> 6, lane = tid & 63;
  const int wm = (wave >> 2) * 128, wn = (wave & 3) * 64;
  const int r15 = lane & 15, quad = lane >> 4;
  const int srow = tid >> 3, scb = tid & 7;
  const int NT = K >> 6;

  const __hip_bfloat16* Ap = A + (size_t)bm * K;
  const __hip_bfloat16* Wp = W + (size_t)bn * K;

  auto stageA = [&](int buf, int k0, int h) {
#pragma unroll
    for (int io = 0; io < 2; ++io) {
      int row = h * 128 + io * 64 + srow;
      int gcb = scb ^ (row & 7);
      load_lds16(Ap + (size_t)row * K + k0 + gcb * 8,
                 &As[buf][(h * 128 + io * 64) * 64] + tid * 8);
    }
  };
  auto stageB = [&](int buf, int k0, int h) {
#pragma unroll
    for (int io = 0; io < 2; ++io) {
      int row = h * 128 + io * 64 + srow;
      int gcb = scb ^ (row & 7);
      load_lds16(Wp + (size_t)row * K + k0 + gcb * 8,
                 &Bs[buf][(h * 128 + io * 64) * 64] + tid * 8);
    }
  };

  floatx4 acc[8][4];
#pragma unroll
  for (int i = 0; i < 8; ++i)
#pragma unroll
    for (int jn = 0; jn < 4; ++jn) acc[i][jn] = (floatx4){0.f, 0.f, 0.f, 0.f};

  stageA(0, 0, 0); stageA(0, 0, 1);
  stageB(0, 0, 0); stageB(0, 0, 1);
  stageA(1, 64, 0); stageA(1, 64, 1);
  asm volatile("s_waitcnt vmcnt(4)" ::: "memory");
  __builtin_amdgcn_s_barrier();
  __builtin_amdgcn_sched_barrier(0);

#define PHASE_BAR() do { __builtin_amdgcn_sched_barrier(0); \
                         __builtin_amdgcn_s_barrier();      \
                         __builtin_amdgcn_sched_barrier(0); } while (0)

  bf16x8 af[4][2], bfr[4][2];
  for (int j = 0; j < NT; ++j) {
    const int cur = j & 1, nxt = cur ^ 1;
    const int k1 = (j + 1) << 6, k2 = (j + 2) << 6;

#pragma unroll
    for (int i = 0; i < 4; ++i) {
      int row = wm + i * 16 + r15;
#pragma unroll
      for (int kc = 0; kc < 2; ++kc)
        af[i][kc] = *(const bf16x8*)&As[cur][row * 64 + (((kc * 4 + quad) ^ (row & 7)) * 8)];
    }
#pragma unroll
    for (int jn = 0; jn < 2; ++jn) {
      int row = wn + jn * 16 + r15;
#pragma unroll
      for (int kc = 0; kc < 2; ++kc)
        bfr[jn][kc] = *(const bf16x8*)&Bs[cur][row * 64 + (((kc * 4 + quad) ^ (row & 7)) * 8)];
    }
    if (j + 1 < NT) stageB(nxt, k1, 0);
    PHASE_BAR();
    __builtin_amdgcn_s_setprio(1);
#pragma unroll
    for (int i = 0; i < 4; ++i)
#pragma unroll
      for (int jn = 0; jn < 2; ++jn)
#pragma unroll
        for (int kc = 0; kc < 2; ++kc)
          acc[i][jn] = __builtin_amdgcn_mfma_f32_16x16x32_bf16(
              af[i][kc], bfr[jn][kc], acc[i][jn], 0, 0, 0);
    __builtin_amdgcn_s_setprio(0);
    PHASE_BAR();

#pragma unroll
    for (int jn = 2; jn < 4; ++jn) {
      int row = wn + jn * 16 + r15;
#pragma unroll
      for (int kc = 0; kc < 2; ++kc)
        bfr[jn][kc] = *(const bf16x8*)&Bs[cur][row * 64 + (((kc * 4 + quad) ^ (row & 7)) * 8)];
    }
    if (j + 1 < NT) stageB(nxt, k1, 1);
    PHASE_BAR();
    __builtin_amdgcn_s_setprio(1);
#pragma unroll
    for (int i = 0; i < 4; ++i)
#pragma unroll
      for (int jn = 2; jn < 4; ++jn)
#pragma unroll
        for (int kc = 0; kc < 2; ++kc)
          acc[i][jn] = __builtin_amdgcn_mfma_f32_16x16x32_bf16(
              af[i][kc], bfr[jn][kc], acc[i][jn], 0, 0, 0);
    __builtin_amdgcn_s_setprio(0);
    PHASE_BAR();

#pragma unroll
    for (int i = 0; i < 4; ++i) {
      int row = wm + (i + 4) * 16 + r15;
#pragma unroll
      for (int kc = 0; kc < 2; ++kc)
        af[i][kc] = *(const bf16x8*)&As[cur][row * 64 + (((kc * 4 + quad) ^ (row & 7)) * 8)];
    }
    PHASE_BAR();
    __builtin_amdgcn_s_setprio(1);
#pragma unroll
    for (int i = 0; i < 4; ++i)
#pragma unroll
      for (int jn = 2; jn < 4; ++jn)
#pragma unroll
        for (int kc = 0; kc < 2; ++kc)
          acc[i + 4][jn] = __builtin_amdgcn_mfma_f32_16x16x32_bf16(
              af[i][kc], bfr[jn][kc], acc[i + 4][jn], 0, 0, 0);
    __builtin_amdgcn_s_setprio(0);
    PHASE_BAR();

    if (j + 2 < NT) { stageA(cur, k2, 0); stageA(cur, k2, 1); }
    if (j < NT - 2) asm volatile("s_waitcnt vmcnt(4)" ::: "memory");
    else            asm volatile("s_waitcnt vmcnt(0)" ::: "memory");
    PHASE_BAR();
    __builtin_amdgcn_s_setprio(1);
#pragma unroll
    for (int i = 0; i < 4; ++i)
#pragma unroll
      for (int jn = 0; jn < 2; ++jn)
#pragma unroll
        for (int kc = 0; kc < 2; ++kc)
          acc[i + 4][jn] = __builtin_amdgcn_mfma_f32_16x16x32_bf16(
              af[i][kc], bfr[jn][kc], acc[i + 4][jn], 0, 0, 0);
    __builtin_amdgcn_s_setprio(0);
    PHASE_BAR();
  }
#undef PHASE_BAR

  const int crow0 = bm + wm + quad * 4;
  const int ccol0 = bn + wn + r15;
#pragma unroll
  for (int jn = 0; jn < 4; ++jn) {
    int col = ccol0 + jn * 16;
    float bv = bias ? bias[col] : 0.f;
    float scale = (qkscale && col < EMB) ? QSCALE : 1.f;
#pragma unroll
    for (int i = 0; i < 8; ++i) {
#pragma unroll
      for (int r = 0; r < 4; ++r) {
        int row = crow0 + i * 16 + r;
        float v = (acc[i][jn][r] + bv) * scale;
        if (relu) v = fmaxf(v, 0.f);
        Cb[(size_t)row * N + col] = __float2bfloat16(v);
      }
    }
  }
}

// ---------------- transpose V: vT[b, c, t] = qkv_bf[t*B+b, 2E + c] ----------
__global__ __launch_bounds__(256) void transpose_v(
    const __hip_bfloat16* __restrict__ qkv, __hip_bfloat16* __restrict__ vT)
{
  __shared__ __hip_bfloat16 tile[64][72];
  int c0 = blockIdx.x * 64, t0 = blockIdx.y * 64, b = blockIdx.z;
  int tid = threadIdx.x;
#pragma unroll
  for (int i = 0; i < 2; ++i) {
    int k = tid * 2 + i;
    int row = k >> 3, col = (k & 7) * 8;
    float4 v = *(const float4*)&qkv[((size_t)(t0 + row) * BATCH + b) * E3 + 2 * EMB + c0 + col];
    __hip_bfloat16 tmp[8];
    *(float4*)tmp = v;
#pragma unroll
    for (int j = 0; j < 8; ++j) tile[row][col + j] = tmp[j];
  }
  __syncthreads();
#pragma unroll
  for (int i = 0; i < 2; ++i) {
    int k = tid * 2 + i;
    int crow = k >> 3, tcol = (k & 7) * 8;
    __hip_bfloat16 tmp[8];
#pragma unroll
    for (int j = 0; j < 8; ++j) tmp[j] = tile[tcol + j][crow];
    *(float4*)&vT[((size_t)(b * EMB + c0 + crow)) * S_LEN + t0 + tcol] = *(float4*)tmp;
  }
}

// ---------------- MFMA flash attention, S^T form, no-max softmax -------------
// 8 waves x 16 q-rows. Q-side operands pre-scaled by log2(e) (q cols at the
// qkv GEMM epilogue, pe via the peQ buffer) so P = 2^(S') with ONE raw
// v_exp_f32 per element (inline asm; libm exp2f carries edge-case VALU work —
// measured regression r4). No setprio: the 8 waves are barrier-lockstep per
// tile, the regime where setprio measured ~0/negative (m190), not the
// independent-block regime where it helped (m191). r4 A/B: with setprio+libm
// exp2f 84.1 us; r3 baseline 78.7 us.
__global__ __launch_bounds__(512, 4) void attn_mfma(
    const __hip_bfloat16* __restrict__ qkv,   // [S*B][E3] bf16 (q pre-scaled)
    const __hip_bfloat16* __restrict__ vT,    // [B][EMB][S] bf16
    const __hip_bfloat16* __restrict__ peT,   // [B][S][PP] bf16 (K'-side)
    const __hip_bfloat16* __restrict__ peQ,   // [B][S][PP] bf16 (Q'-side, xlog2e)
    __hip_bfloat16* __restrict__ ctx)         // [S*B][EMB] bf16
{
  __shared__ __bf16 Ks[2][4096];   // 16 KB  [key][d]  swizzled (k part)
  __shared__ __bf16 Kp[2][4096];   // 16 KB  [key][p]  swizzled (pe part)
  __shared__ __bf16 Vs[2][4096];   // 16 KB  [d][t]    swizzled
  __shared__ __bf16 Ps[8192];      // 16 KB  per wave: [query][key] swizzled
  int tid = threadIdx.x;
  int q0 = blockIdx.x * 128, h = blockIdx.y, b = blockIdx.z;
  int w = tid >> 6, lane = tid & 63, quad = lane >> 4, r15 = lane & 15;
  int srow = tid >> 3, scb = tid & 7;
  int x7 = r15 & 7;

  const __hip_bfloat16* kbase = qkv + EMB + (size_t)h * DH;
  const __hip_bfloat16* vbase = vT + ((size_t)b * EMB + h * DH) * S_LEN;
  const __hip_bfloat16* pkbase = peT + (size_t)b * S_LEN * PP;
  const __hip_bfloat16* pqbase = peQ + (size_t)b * S_LEN * PP;

  // ---- Q' fragments straight to registers (B-operand layout) ----
  bf16x8 qa[4];
  {
    int qrow = q0 + w * 16 + r15;
#pragma unroll
    for (int kc = 0; kc < 2; ++kc)
      qa[kc] = *(const bf16x8*)&qkv[
          ((size_t)qrow * BATCH + b) * E3 + h * DH + kc * 32 + quad * 8];
#pragma unroll
    for (int kc = 0; kc < 2; ++kc)
      qa[2 + kc] = *(const bf16x8*)&pqbase[
          (size_t)qrow * PP + kc * 32 + quad * 8];
  }

  // ---- stage first K'/V tile ----
  {
    int row = srow;
    int gcb = scb ^ (row & 7);
    load_lds16(kbase + ((size_t)row * BATCH + b) * E3 + gcb * 8, Ks[0] + tid * 8);
    load_lds16(pkbase + (size_t)row * PP + gcb * 8, Kp[0] + tid * 8);
    load_lds16(vbase + (size_t)row * S_LEN + gcb * 8, Vs[0] + tid * 8);
  }
  __syncthreads();

  floatx4 of[4];
#pragma unroll
  for (int j = 0; j < 4; ++j) of[j] = (floatx4){0.f, 0.f, 0.f, 0.f};
  float lp = 0.f;

  __bf16* pw = Ps + w * 1024;

  for (int kt = 0; kt < 32; ++kt) {
    int cur = kt & 1;
    int t0 = kt * 64;
    // ---- stage next K'/V tile into the other buffer ----
    if (kt < 31) {
      int tn = t0 + 64;
      int nb = cur ^ 1;
      int row = srow;
      int gcb = scb ^ (row & 7);
      load_lds16(kbase + ((size_t)(tn + row) * BATCH + b) * E3 + gcb * 8,
                 Ks[nb] + tid * 8);
      load_lds16(pkbase + (size_t)(tn + row) * PP + gcb * 8,
                 Kp[nb] + tid * 8);
      load_lds16(vbase + (size_t)row * S_LEN + tn + gcb * 8,
                 Vs[nb] + tid * 8);
    }

    // ---- S^T = K' Q'^T (A = K' rows=keys, B = Q'^T cols=queries) ----
    floatx4 sf[4];
#pragma unroll
    for (int j = 0; j < 4; ++j) sf[j] = (floatx4){0.f, 0.f, 0.f, 0.f};
#pragma unroll
    for (int j = 0; j < 4; ++j) {
      int rowk = j * 16 + r15;
      int rx = rowk & 7;
      bf16x8 kf0 = *(const bf16x8*)&Ks[cur][rowk * 64 + ((quad ^ rx)) * 8];
      bf16x8 kf1 = *(const bf16x8*)&Ks[cur][rowk * 64 + (((4 + quad) ^ rx)) * 8];
      bf16x8 kp0 = *(const bf16x8*)&Kp[cur][rowk * 64 + ((quad ^ rx)) * 8];
      bf16x8 kp1 = *(const bf16x8*)&Kp[cur][rowk * 64 + (((4 + quad) ^ rx)) * 8];
      sf[j] = __builtin_amdgcn_mfma_f32_16x16x32_bf16(kf0, qa[0], sf[j], 0, 0, 0);
      sf[j] = __builtin_amdgcn_mfma_f32_16x16x32_bf16(kf1, qa[1], sf[j], 0, 0, 0);
      sf[j] = __builtin_amdgcn_mfma_f32_16x16x32_bf16(kp0, qa[2], sf[j], 0, 0, 0);
      sf[j] = __builtin_amdgcn_mfma_f32_16x16x32_bf16(kp1, qa[3], sf[j], 0, 0, 0);
    }

    // ---- 2^S (args pre-scaled by log2e; bounded), pack P^T -> LDS ----
#pragma unroll
    for (int j = 0; j < 4; ++j) {
      float e0 = hw_exp2(sf[j][0]);
      float e1 = hw_exp2(sf[j][1]);
      float e2 = hw_exp2(sf[j][2]);
      float e3 = hw_exp2(sf[j][3]);
      lp += (e0 + e1) + (e2 + e3);
      __hip_bfloat16 t4[4];
      t4[0] = __float2bfloat16(e0); t4[1] = __float2bfloat16(e1);
      t4[2] = __float2bfloat16(e2); t4[3] = __float2bfloat16(e3);
      int addr = r15 * 64 + (((j * 2 + (quad >> 1)) ^ x7) * 8) + (quad & 1) * 4;
      *(float2*)&pw[addr] = *(float2*)t4;
    }
    __asm__ volatile("s_waitcnt lgkmcnt(0)" ::: "memory");

    // ---- O^T += V^T P^T  (A = V^T rows=d, B = P^T cols=queries) ----
    bf16x8 pb0 = *(const bf16x8*)&pw[r15 * 64 + ((quad ^ x7) * 8)];
    bf16x8 pb1 = *(const bf16x8*)&pw[r15 * 64 + (((4 + quad) ^ x7) * 8)];
#pragma unroll
    for (int jd = 0; jd < 4; ++jd) {
      int rowd = jd * 16 + r15;
      bf16x8 vb0 = *(const bf16x8*)&Vs[cur][rowd * 64 + (quad ^ (rowd & 7)) * 8];
      bf16x8 vb1 = *(const bf16x8*)&Vs[cur][rowd * 64 + ((4 + quad) ^ (rowd & 7)) * 8];
      of[jd] = __builtin_amdgcn_mfma_f32_16x16x32_bf16(vb0, pb0, of[jd], 0, 0, 0);
      of[jd] = __builtin_amdgcn_mfma_f32_16x16x32_bf16(vb1, pb1, of[jd], 0, 0, 0);
    }
    __syncthreads();   // waves done with bufs[cur]; next-tile staging drained
  }

  // ---- epilogue: reduce l over quads, O^T / l, packed 8B stores ----
  {
    float l = lp;
    l += __shfl_xor(l, 16, 64);
    l += __shfl_xor(l, 32, 64);
    float inv = 1.f / l;
    size_t rbase = ((size_t)(q0 + w * 16 + r15) * BATCH + b) * EMB + h * DH;
#pragma unroll
    for (int jd = 0; jd < 4; ++jd) {
      __hip_bfloat16 o4[4];
      o4[0] = __float2bfloat16(of[jd][0] * inv);
      o4[1] = __float2bfloat16(of[jd][1] * inv);
      o4[2] = __float2bfloat16(of[jd][2] * inv);
      o4[3] = __float2bfloat16(of[jd][3] * inv);
      *(float2*)&ctx[rbase + jd * 16 + quad * 4] = *(float2*)o4;
    }
  }
}

// ---------------- layernorm(x1+x2)*g + b, fp32 out + optional bf16 out -------
__global__ __launch_bounds__(256) void ln_kernel(
    const float* __restrict__ x1, const float* __restrict__ x2,
    const float* __restrict__ g, const float* __restrict__ bb,
    float* __restrict__ out, __hip_bfloat16* __restrict__ out_bf)
{
  int row = blockIdx.x;
  int tid = threadIdx.x;
  const float* p1 = x1 + (size_t)row * EMB;
  const float* p2 = x2 + (size_t)row * EMB;
  float4 v1 = *(const float4*)&p1[tid * 4];
  float4 v2 = *(const float4*)&p2[tid * 4];
  float x[4] = {v1.x + v2.x, v1.y + v2.y, v1.z + v2.z, v1.w + v2.w};
  float s = x[0] + x[1] + x[2] + x[3];
  float s2 = x[0] * x[0] + x[1] * x[1] + x[2] * x[2] + x[3] * x[3];
#pragma unroll
  for (int off = 32; off >= 1; off >>= 1) {
    s  += __shfl_xor(s, off, 64);
    s2 += __shfl_xor(s2, off, 64);
  }
  __shared__ float ws1[4], ws2[4];
  int wid = tid >> 6, lane = tid & 63;
  if (lane == 0) { ws1[wid] = s; ws2[wid] = s2; }
  __syncthreads();
  s  = ws1[0] + ws1[1] + ws1[2] + ws1[3];
  s2 = ws2[0] + ws2[1] + ws2[2] + ws2[3];
  float mean = s * (1.f / EMB);
  float var  = s2 * (1.f / EMB) - mean * mean;
  float inv  = rsqrtf(var + 1e-5f);
  float4 gv = *(const float4*)&g[tid * 4];
  float4 bv = *(const float4*)&bb[tid * 4];
  float4 o;
  o.x = (x[0] - mean) * inv * gv.x + bv.x;
  o.y = (x[1] - mean) * inv * gv.y + bv.y;
  o.z = (x[2] - mean) * inv * gv.z + bv.z;
  o.w = (x[3] - mean) * inv * gv.w + bv.w;
  *(float4*)&out[(size_t)row * EMB + tid * 4] = o;
  if (out_bf) {
    __hip_bfloat16 t[4];
    t[0] = __float2bfloat16(o.x); t[1] = __float2bfloat16(o.y);
    t[2] = __float2bfloat16(o.z); t[3] = __float2bfloat16(o.w);
    *(float2*)&out_bf[(size_t)row * EMB + tid * 4] = *(float2*)t;
  }
}

// ---------------- layernorm(x1+x2+x3)*g + b, fp32 out (split-K ff2 sum) -----
__global__ __launch_bounds__(256) void ln3_kernel(
    const float* __restrict__ x1, const float* __restrict__ x2,
    const float* __restrict__ x3,
    const float* __restrict__ g, const float* __restrict__ bb,
    float* __restrict__ out)
{
  int row = blockIdx.x;
  int tid = threadIdx.x;
  const float* p1 = x1 + (size_t)row * EMB;
  const float* p2 = x2 + (size_t)row * EMB;
  const float* p3 = x3 + (size_t)row * EMB;
  float4 v1 = *(const float4*)&p1[tid * 4];
  float4 v2 = *(const float4*)&p2[tid * 4];
  float4 v3 = *(const float4*)&p3[tid * 4];
  float x[4] = {v1.x + v2.x + v3.x, v1.y + v2.y + v3.y,
                v1.z + v2.z + v3.z, v1.w + v2.w + v3.w};
  float s = x[0] + x[1] + x[2] + x[3];
  float s2 = x[0] * x[0] + x[1] * x[1] + x[2] * x[2] + x[3] * x[3];
#pragma unroll
  for (int off = 32; off >= 1; off >>= 1) {
    s  += __shfl_xor(s, off, 64);
    s2 += __shfl_xor(s2, off, 64);
  }
  __shared__ float ws1[4], ws2[4];
  int wid = tid >> 6, lane = tid & 63;
  if (lane == 0) { ws1[wid] = s; ws2[wid] = s2; }
  __syncthreads();
  s  = ws1[0] + ws1[1] + ws1[2] + ws1[3];
  s2 = ws2[0] + ws2[1] + ws2[2] + ws2[3];
  float mean = s * (1.f / EMB);
  float var  = s2 * (1.f / EMB) - mean * mean;
  float inv  = rsqrtf(var + 1e-5f);
  float4 gv = *(const float4*)&g[tid * 4];
  float4 bv = *(const float4*)&bb[tid * 4];
  float4 o;
  o.x = (x[0] - mean) * inv * gv.x + bv.x;
  o.y = (x[1] - mean) * inv * gv.y + bv.y;
  o.z = (x[2] - mean) * inv * gv.z + bv.z;
  o.w = (x[3] - mean) * inv * gv.w + bv.w;
  *(float4*)&out[(size_t)row * EMB + tid * 4] = o;
}

extern "C" void kernel_launch(void* const* d_in, const int* in_sizes, int n_in,
                              void* d_out, int out_size, void* d_ws, size_t ws_size,
                              hipStream_t stream)
{
  const float* src       = (const float*)d_in[0];
  const float* pos_embed = (const float*)d_in[1];
  const float* in_proj_w = (const float*)d_in[2];
  const float* in_proj_b = (const float*)d_in[3];
  const float* out_w     = (const float*)d_in[4];
  const float* out_b     = (const float*)d_in[5];
  const float* lin1_w    = (const float*)d_in[6];
  const float* lin1_b    = (const float*)d_in[7];
  const float* lin2_w    = (const float*)d_in[8];
  const float* lin2_b    = (const float*)d_in[9];
  const float* ln1_g     = (const float*)d_in[10];
  const float* ln1_b     = (const float*)d_in[11];
  const float* ln2_g     = (const float*)d_in[12];
  const float* ln2_b     = (const float*)d_in[13];
  const float* pos_w     = (const float*)d_in[14];
  const float* pos_b     = (const float*)d_in[15];
  float* out = (float*)d_out;
  float* ws  = (float*)d_ws;

  // ---- workspace layout (float units) ----
  __hip_bfloat16* peT    = (__hip_bfloat16*)ws;                // 262,144 el -> 131,072 fl
  __hip_bfloat16* peQ    = (__hip_bfloat16*)(ws + 131072);     // 262,144 el -> 262,144 fl
  __hip_bfloat16* qkv_bf = (__hip_bfloat16*)(ws + 8519680);    // 12,582,912 el -> 14,811,136
  __hip_bfloat16* vT_bf  = (__hip_bfloat16*)(ws + 14811136);   // 4,194,304 el -> 16,908,288
  __hip_bfloat16* src_bf = (__hip_bfloat16*)(ws + 16908288);   // 4,194,304 el -> 19,005,440
  __hip_bfloat16* inw_bf  = (__hip_bfloat16*)(ws + 19005440);  // 3,145,728 el -> 20,578,304
  __hip_bfloat16* outw_bf = (__hip_bfloat16*)(ws + 20578304);  // 1,048,576 el -> 21,102,592
  __hip_bfloat16* ctx_bf = (__hip_bfloat16*)(ws + 21102592);   // 4,194,304 el -> 23,199,744
  __hip_bfloat16* l1w_bf = (__hip_bfloat16*)(ws + 23199744);   // 4,194,304 el -> 25,296,896
  __hip_bfloat16* l2w_bf = (__hip_bfloat16*)(ws + 25296896);   // 4,194,304 el -> 27,394,048
  float* proj            = ws + 27394048;                      // 4,194,304 -> 31,588,352
  // phase-2 reuse (peT/peQ/qkv/vT/src_bf dead after their consumers):
  __hip_bfloat16* x_bf   = (__hip_bfloat16*)ws;                // 4,194,304 el -> 2,097,152 fl
  float* xbuf            = ws + 2097152;                       // 4,194,304 -> 6,291,456
  __hip_bfloat16* h1_bf  = (__hip_bfloat16*)(ws + 6291456);    // 16,777,216 el -> 14,680,064 fl
  float* proj2           = ws + 14811136;                      // 4,194,304 -> 19,005,440 (old vT+src_bf region)

  const int M = S_LEN * BATCH;  // 4096 rows, row = s*B + b

  cvt5_kernel<<<8192, 256, 0, stream>>>(
      src, src_bf, in_proj_w, inw_bf, out_w, outw_bf,
      lin1_w, l1w_bf, lin2_w, l2w_bf);
  pe_kernel<<<dim3(S_LEN / 64, BATCH), 64, 0, stream>>>(pos_embed, pos_w, pos_b, peT, peQ);
  // qkv = src @ in_proj_w^T + b, q-cols pre-scaled by 0.125*log2e
  gemm256_bf16<<<dim3(E3 / 256, M / 256), 512, 0, stream>>>(
      src_bf, inw_bf, in_proj_b, qkv_bf, M, E3, EMB, 0, 1);
  transpose_v<<<dim3(EMB / 64, S_LEN / 64, BATCH), 256, 0, stream>>>(qkv_bf, vT_bf);
  attn_mfma<<<dim3(S_LEN / 128, NH, BATCH), 512, 0, stream>>>(
      qkv_bf, vT_bf, peT, peQ, ctx_bf);
  // attn_out = ctx @ out_w^T + b
  gemm_bf16<2, 4><<<dim3(EMB / 128, M / 64, 1), 256, 0, stream>>>(
      ctx_bf, outw_bf, out_b, proj, nullptr, M, EMB, EMB, 0, 0, EMB, EMB, 0, 0, 0);
  ln_kernel<<<dim3(M), 256, 0, stream>>>(src, proj, ln1_g, ln1_b, xbuf, x_bf);
  // ff1 = relu(x @ lin1_w^T + b)  (8-phase 256^2)
  gemm256_bf16<<<dim3(FF / 256, M / 256), 512, 0, stream>>>(
      x_bf, l1w_bf, lin1_b, h1_bf, M, FF, EMB, 1, 0);
  // ff2 split-K x2: chunk z covers K-cols [z*2048, z*2048+2048); partials to
  // proj (z=0, +bias) and proj2 (z=1; strideC = proj2 - proj).
  gemm_bf16<4, 4><<<dim3(EMB / 128, M / 128, 2), 256, 0, stream>>>(
      h1_bf, l2w_bf, lin2_b, proj, nullptr, M, EMB, FF / 2, 0, 0,
      FF, FF, FF / 2, FF / 2, (long)(proj2 - proj));
  ln3_kernel<<<dim3(M), 256, 0, stream>>>(xbuf, proj, proj2, ln2_g, ln2_b, out);
}